// Round 31
// baseline (66.915 us; speedup 1.0000x reference)
//
#include <hip/hip_runtime.h>
#include <stdint.h>

static constexpr int   Bn      = 32;
static constexpr int   Tn      = 2000;
static constexpr int   Hn      = 512;
static constexpr int   Ln      = 256;     // max_label_len
static constexpr float kThresh = 0.95f;
static constexpr int   TCHUNK  = 10;      // meta granularity (consumer chunk)
static constexpr int   NTCH    = Tn / TCHUNK;   // 200
static constexpr int   MSTRIDE = 256;           // meta entries per row (padded)
static constexpr unsigned PUBF = 0x40000000u;   // published flag (low word)

// ---------------------------------------------------------------------------
// Fused producer-consumer CIF. R31 = R30 (53.8 us best) with the proven
// granularity lever pushed once more: TCHUNK 20->10 (200 chunks, 6400
// consumers). Consumers beyond the 4608-block residency cap queue BENIGNLY:
// ordered by tc, and late-tc consumers need late metas anyway (unlike R24,
// where all consumers were needed concurrently for TLP). Producer publishes
// meta every 10 steps: the 20-step rotation iteration is split q0,q1 |
// publish | q2a(2 steps) is WRONG -- 10 steps = q0,q1,q2-first-half. The
// iteration is restructured as: publish(2c); q0; q1; q2 first 2 elems;
// publish(2c+1) [state at t=20c+10]; q2 last 2; q3; q4. All publishes are
// lane-0-only, off the serial chain.
//
// Producer: LDS-staged alpha row, depth-5 rotation of named float4
// (ds_read-fed, no vmem/arrays in chain). Consumers (one per (tc, b)):
// spin on meta[tc], bit-exact replay, exclusive ownership of segments
// CLOSING in the chunk (walk-back derives the straddler opening),
// ascending-t accumulation = reference op order -> absmax 0.0; tc=NTCH-1
// zero-fills [fc,256). No atomics, no pre-zero pass.
// ---------------------------------------------------------------------------
__global__ __launch_bounds__(64, 1) void cif_fused_kernel(
    const float* __restrict__ hidden,
    const float* __restrict__ alphas,
    uint64_t* __restrict__ meta,     // [Bn*MSTRIDE]
    float* __restrict__ out) {
  const int lane = threadIdx.x;
  __shared__ __align__(16) float alds[Tn + 64];   // +pad: tail prefetch safe

  if (blockIdx.x < Bn) {
    // ---------------- producer: serial scan for row b ----------------
    __builtin_amdgcn_s_setprio(3);
    const int b = blockIdx.x;
    {  // stage row -> LDS, coalesced (one-time cost, outside the chain)
      const float4* __restrict__ arow =
          reinterpret_cast<const float4*>(alphas + (size_t)b * Tn);
      for (int i = lane; i < Tn / 4; i += 64)
        *reinterpret_cast<float4*>(&alds[4 * i]) = arow[i];
      for (int i = Tn / 4 + lane; i < (Tn + 64) / 4; i += 64)
        *reinterpret_cast<float4*>(&alds[4 * i]) =
            make_float4(0.f, 0.f, 0.f, 0.f);
    }
    __syncthreads();

    const float4* __restrict__ lds4 =
        reinterpret_cast<const float4*>(&alds[0]);
    float I  = 0.0f;
    int   fc = 0;

    float4 q0 = lds4[0], q1 = lds4[1], q2 = lds4[2], q3 = lds4[3],
           q4 = lds4[4];
    int rd = 5;

    auto step1 = [&](float a) {
      const float integ = I + a;              // reference op order
      const bool  fire  = integ > kThresh;
      I  = fire ? (integ - 1.0f) : integ;
      fc += fire ? 1 : 0;
    };
    auto step4 = [&](const float4& q) {
      step1(q.x); step1(q.y); step1(q.z); step1(q.w);
    };
    auto publish = [&](int chunk) {
      if (lane == 0) {
        const uint64_t v = ((uint64_t)__float_as_uint(I) << 32) |
                           (uint64_t)(PUBF | (unsigned)fc);
        __hip_atomic_store(&meta[(size_t)b * MSTRIDE + chunk], v,
                           __ATOMIC_RELAXED, __HIP_MEMORY_SCOPE_AGENT);
      }
    };

    for (int c = 0; c < 100; ++c) {           // 20 steps per iteration
      publish(2 * c);                         // state at t = 20c
      step4(q0); q0 = lds4[rd + 0];           // t = 20c .. 20c+3
      step4(q1); q1 = lds4[rd + 1];           // t = 20c+4 .. 20c+7
      step1(q2.x); step1(q2.y);               // t = 20c+8, 20c+9
      publish(2 * c + 1);                     // state at t = 20c+10
      step1(q2.z); step1(q2.w);               // t = 20c+10, 20c+11
      q2 = lds4[rd + 2];
      step4(q3); q3 = lds4[rd + 3];           // t = 20c+12 .. 20c+15
      step4(q4); q4 = lds4[rd + 4];           // t = 20c+16 .. 20c+19
      rd += 5;
    }
    return;
  }

  // ---------------- consumer: (chunk tc, row b) ----------------
  const int idx = blockIdx.x - Bn;
  const int b   = idx & (Bn - 1);
  const int tc  = idx >> 5;                 // low blockIdx -> low tc
  const int t_start = tc * TCHUNK;
  const int col = lane * 8;                 // 8 floats/thread over H=512

  auto wait_meta = [&](int c) -> uint64_t {
    const uint64_t* p = &meta[(size_t)b * MSTRIDE + c];
    uint64_t v;
    for (;;) {
      v = __hip_atomic_load(p, __ATOMIC_RELAXED, __HIP_MEMORY_SCOPE_AGENT);
      if ((unsigned)v & PUBF) break;
      __builtin_amdgcn_s_sleep(16);
    }
    return v;
  };

  const float* __restrict__ arow = alphas + (size_t)b * Tn;

  // Chunk-start state (bit-exact from producer).
  float I; int s;
  if (tc == 0) { I = 0.0f; s = 0; }
  else {
    const uint64_t v = wait_meta(tc);
    I = __uint_as_float((unsigned)(v >> 32));
    s = (int)((unsigned)v & 0xFFFFu);
  }

  // Walk back: find t_prev (last fire before t_start) and its remainder.
  int   t_prev   = -1;
  float rem_prev = 0.0f;
  for (int k = 1; tc - k >= 0 && t_prev < 0; ++k) {
    const int ck = tc - k;
    float Ik;
    if (ck == 0) Ik = 0.0f;
    else {
      const uint64_t v = wait_meta(ck);
      Ik = __uint_as_float((unsigned)(v >> 32));
    }
    const float* __restrict__ ap = arow + ck * TCHUNK;
    int lt = -1; float lrem = 0.0f;
#pragma unroll
    for (int j = 0; j < TCHUNK; ++j) {
      const float a     = ap[j];               // uniform scalar load
      const float integ = Ik + a;              // reference op order
      const bool  fire  = integ > kThresh;
      if (fire) { lt = ck * TCHUNK + j; lrem = a - (1.0f - Ik); }
      Ik = fire ? (integ - 1.0f) : integ;
    }
    if (lt >= 0) { t_prev = lt; rem_prev = lrem; }
  }

  const float* __restrict__ hb = hidden + (size_t)b * Tn * Hn + col;
  float4 acc0 = make_float4(0.f, 0.f, 0.f, 0.f);
  float4 acc1 = make_float4(0.f, 0.f, 0.f, 0.f);

  auto loadh0 = [&](int t) -> float4 {
    return *reinterpret_cast<const float4*>(hb + (size_t)t * Hn);
  };
  auto loadh1 = [&](int t) -> float4 {
    return *reinterpret_cast<const float4*>(hb + (size_t)t * Hn + 4);
  };

  if (t_prev >= 0) {            // opening: frame = rem * h[t_prev]
    const float4 h0 = loadh0(t_prev);
    const float4 h1 = loadh1(t_prev);
    acc0.x = rem_prev * h0.x; acc0.y = rem_prev * h0.y;
    acc0.z = rem_prev * h0.z; acc0.w = rem_prev * h0.w;
    acc1.x = rem_prev * h1.x; acc1.y = rem_prev * h1.y;
    acc1.z = rem_prev * h1.z; acc1.w = rem_prev * h1.w;
  }
  for (int t = t_prev + 1; t < t_start; ++t) {   // straddler interior rows
    const float a   = arow[t];
    const float4 h0 = loadh0(t);
    const float4 h1 = loadh1(t);
    acc0.x += a * h0.x; acc0.y += a * h0.y;
    acc0.z += a * h0.z; acc0.w += a * h0.w;
    acc1.x += a * h1.x; acc1.y += a * h1.y;
    acc1.z += a * h1.z; acc1.w += a * h1.w;
  }

  // Replay chunk tc with depth-2 row prefetch; close/store owned segments.
  float4 c0 = loadh0(t_start);
  float4 c1 = loadh1(t_start);
  for (int j = 0; j < TCHUNK; ++j) {
    const int t  = t_start + j;
    const int tn = (j + 1 < TCHUNK) ? t + 1 : t;   // clamp in-chunk
    const float4 n0 = loadh0(tn);            // issue BEFORE consuming c0/c1
    const float4 n1 = loadh1(tn);
    const float a     = arow[t];             // uniform scalar load
    const float integ = I + a;               // reference op order
    const bool  fire  = integ > kThresh;     // wave-uniform
    if (fire) {
      const float cw = 1.0f - I;             // dist_completion
      acc0.x += cw * c0.x; acc0.y += cw * c0.y;
      acc0.z += cw * c0.z; acc0.w += cw * c0.w;
      acc1.x += cw * c1.x; acc1.y += cw * c1.y;
      acc1.z += cw * c1.z; acc1.w += cw * c1.w;
      if (s < Ln) {
        float* op = out + ((size_t)b * Ln + s) * Hn + col;
        *reinterpret_cast<float4*>(op)     = acc0;
        *reinterpret_cast<float4*>(op + 4) = acc1;
      }
      const float rem = a - cw;              // remainds -> opens next segment
      acc0.x = rem * c0.x; acc0.y = rem * c0.y;
      acc0.z = rem * c0.z; acc0.w = rem * c0.w;
      acc1.x = rem * c1.x; acc1.y = rem * c1.y;
      acc1.z = rem * c1.z; acc1.w = rem * c1.w;
      s += 1;
      I  = integ - 1.0f;
    } else {
      acc0.x += a * c0.x; acc0.y += a * c0.y;
      acc0.z += a * c0.z; acc0.w += a * c0.w;
      acc1.x += a * c1.x; acc1.y += a * c1.y;
      acc1.z += a * c1.z; acc1.w += a * c1.w;
      I = integ;
    }
    c0 = n0; c1 = n1;
  }
  // Open tail is owned by consumer (tc+1); nothing more to store...
  if (tc == NTCH - 1) {                      // ...except zero-fill at the end
    const float4 z = make_float4(0.f, 0.f, 0.f, 0.f);
    for (int s2 = s; s2 < Ln; ++s2) {
      float* op = out + ((size_t)b * Ln + s2) * Hn + col;
      *reinterpret_cast<float4*>(op)     = z;
      *reinterpret_cast<float4*>(op + 4) = z;
    }
  }
}

extern "C" void kernel_launch(void* const* d_in, const int* in_sizes, int n_in,
                              void* d_out, int out_size, void* d_ws, size_t ws_size,
                              hipStream_t stream) {
  const float* hidden = (const float*)d_in[0];
  const float* alphas = (const float*)d_in[1];
  float* out = (float*)d_out;

  // ws layout: meta[Bn*MSTRIDE] u64 (64 KB, memset each call -- poison 0xAA
  // would read as published since bit30 of 0xAAAAAAAA is set).
  uint64_t* meta = (uint64_t*)d_ws;
  hipMemsetAsync(meta, 0, (size_t)Bn * MSTRIDE * sizeof(uint64_t), stream);

  const int nblocks = Bn + NTCH * Bn;   // 32 producers + 6400 consumers
  cif_fused_kernel<<<nblocks, 64, 0, stream>>>(hidden, alphas, meta, out);
}

// Round 32
// 54.729 us; speedup vs baseline: 1.2226x; 1.2226x over previous
//
#include <hip/hip_runtime.h>
#include <stdint.h>

static constexpr int   Bn      = 32;
static constexpr int   Tn      = 2000;
static constexpr int   Hn      = 512;
static constexpr int   Ln      = 256;     // max_label_len
static constexpr float kThresh = 0.95f;
static constexpr int   TCHUNK  = 20;      // meta granularity (consumer chunk)
static constexpr int   NTCH    = Tn / TCHUNK;   // 100
static constexpr int   MSTRIDE = 128;           // meta entries per row (padded)
static constexpr unsigned PUBF = 0x40000000u;   // published flag (low word)

// ---------------------------------------------------------------------------
// Fused producer-consumer CIF — R30 restored verbatim (session best:
// 53.8 us, absmax 0.0). TCHUNK=20, one consumer per (chunk, row) = 3200
// consumers + 32 producers, all co-resident at the stable allocator
// equilibrium (LDS 8704 -> VGPR 44, producer's depth-5 LDS rotation
// unspilled). The granularity curve is fully mapped: TCHUNK 40 = 56.1,
// 20 = 53.8, 10 = 66.9 (R31: >residency queuing + mid-iteration publishes
// slowed the chain). All other axes proven worse or null in R24-R28.
//
// Producer (blocks 0..31): LDS-staged alpha row, serial chain via depth-5
// rotation of named float4 (ds_read-fed, no vmem/arrays in the chain),
// meta = ONE relaxed 8-B atomic per 20 steps (packed (integrate, PUB|fc);
// the meta IS the flag, no fence needed).
// Consumers (one per (chunk tc, row b)): spin with s_sleep on meta[tc],
// bit-exact replay of chunk tc from the packed state, exclusive ownership
// of segments CLOSING in the chunk (walk-back re-derives the straddler
// opening), ascending-t accumulation = reference op order -> absmax 0.0;
// tc=NTCH-1 zero-fills [fc,256). No atomics, no pre-zero pass.
// ---------------------------------------------------------------------------
__global__ __launch_bounds__(64, 1) void cif_fused_kernel(
    const float* __restrict__ hidden,
    const float* __restrict__ alphas,
    uint64_t* __restrict__ meta,     // [Bn*MSTRIDE]
    float* __restrict__ out) {
  const int lane = threadIdx.x;
  __shared__ __align__(16) float alds[Tn + 64];   // +pad: tail prefetch safe

  if (blockIdx.x < Bn) {
    // ---------------- producer: serial scan for row b ----------------
    __builtin_amdgcn_s_setprio(3);
    const int b = blockIdx.x;
    {  // stage row -> LDS, coalesced (one-time cost, outside the chain)
      const float4* __restrict__ arow =
          reinterpret_cast<const float4*>(alphas + (size_t)b * Tn);
      for (int i = lane; i < Tn / 4; i += 64)
        *reinterpret_cast<float4*>(&alds[4 * i]) = arow[i];
      for (int i = Tn / 4 + lane; i < (Tn + 64) / 4; i += 64)
        *reinterpret_cast<float4*>(&alds[4 * i]) =
            make_float4(0.f, 0.f, 0.f, 0.f);
    }
    __syncthreads();

    const float4* __restrict__ lds4 =
        reinterpret_cast<const float4*>(&alds[0]);
    float I  = 0.0f;
    int   fc = 0;

    float4 q0 = lds4[0], q1 = lds4[1], q2 = lds4[2], q3 = lds4[3],
           q4 = lds4[4];
    int rd = 5;

    auto step4 = [&](const float4& q) {
#pragma unroll
      for (int j = 0; j < 4; ++j) {
        const float a = (j == 0) ? q.x : (j == 1) ? q.y : (j == 2) ? q.z : q.w;
        const float integ = I + a;            // reference op order
        const bool  fire  = integ > kThresh;
        I  = fire ? (integ - 1.0f) : integ;
        fc += fire ? 1 : 0;
      }
    };

    for (int c = 0; c < 100; ++c) {           // 20 steps per iteration
      if (lane == 0) {                        // state at t = 20c -> chunk c
        const uint64_t v = ((uint64_t)__float_as_uint(I) << 32) |
                           (uint64_t)(PUBF | (unsigned)fc);
        __hip_atomic_store(&meta[(size_t)b * MSTRIDE + c], v,
                           __ATOMIC_RELAXED, __HIP_MEMORY_SCOPE_AGENT);
      }
      step4(q0); q0 = lds4[rd + 0];           // reload right after consume
      step4(q1); q1 = lds4[rd + 1];
      step4(q2); q2 = lds4[rd + 2];
      step4(q3); q3 = lds4[rd + 3];
      step4(q4); q4 = lds4[rd + 4];
      rd += 5;
    }
    return;
  }

  // ---------------- consumer: (chunk tc, row b) ----------------
  const int idx = blockIdx.x - Bn;
  const int b   = idx & (Bn - 1);
  const int tc  = idx >> 5;                 // low blockIdx -> low tc
  const int t_start = tc * TCHUNK;
  const int col = lane * 8;                 // 8 floats/thread over H=512

  auto wait_meta = [&](int c) -> uint64_t {
    const uint64_t* p = &meta[(size_t)b * MSTRIDE + c];
    uint64_t v;
    for (;;) {
      v = __hip_atomic_load(p, __ATOMIC_RELAXED, __HIP_MEMORY_SCOPE_AGENT);
      if ((unsigned)v & PUBF) break;
      __builtin_amdgcn_s_sleep(16);
    }
    return v;
  };

  const float* __restrict__ arow = alphas + (size_t)b * Tn;

  // Chunk-start state (bit-exact from producer).
  float I; int s;
  if (tc == 0) { I = 0.0f; s = 0; }
  else {
    const uint64_t v = wait_meta(tc);
    I = __uint_as_float((unsigned)(v >> 32));
    s = (int)((unsigned)v & 0xFFFFu);
  }

  // Walk back: find t_prev (last fire before t_start) and its remainder.
  int   t_prev   = -1;
  float rem_prev = 0.0f;
  for (int k = 1; tc - k >= 0 && t_prev < 0; ++k) {
    const int ck = tc - k;
    float Ik;
    if (ck == 0) Ik = 0.0f;
    else {
      const uint64_t v = wait_meta(ck);
      Ik = __uint_as_float((unsigned)(v >> 32));
    }
    const float* __restrict__ ap = arow + ck * TCHUNK;
    int lt = -1; float lrem = 0.0f;
#pragma unroll
    for (int j = 0; j < TCHUNK; ++j) {
      const float a     = ap[j];               // uniform scalar load
      const float integ = Ik + a;              // reference op order
      const bool  fire  = integ > kThresh;
      if (fire) { lt = ck * TCHUNK + j; lrem = a - (1.0f - Ik); }
      Ik = fire ? (integ - 1.0f) : integ;
    }
    if (lt >= 0) { t_prev = lt; rem_prev = lrem; }
  }

  const float* __restrict__ hb = hidden + (size_t)b * Tn * Hn + col;
  float4 acc0 = make_float4(0.f, 0.f, 0.f, 0.f);
  float4 acc1 = make_float4(0.f, 0.f, 0.f, 0.f);

  auto loadh0 = [&](int t) -> float4 {
    return *reinterpret_cast<const float4*>(hb + (size_t)t * Hn);
  };
  auto loadh1 = [&](int t) -> float4 {
    return *reinterpret_cast<const float4*>(hb + (size_t)t * Hn + 4);
  };

  if (t_prev >= 0) {            // opening: frame = rem * h[t_prev]
    const float4 h0 = loadh0(t_prev);
    const float4 h1 = loadh1(t_prev);
    acc0.x = rem_prev * h0.x; acc0.y = rem_prev * h0.y;
    acc0.z = rem_prev * h0.z; acc0.w = rem_prev * h0.w;
    acc1.x = rem_prev * h1.x; acc1.y = rem_prev * h1.y;
    acc1.z = rem_prev * h1.z; acc1.w = rem_prev * h1.w;
  }
  for (int t = t_prev + 1; t < t_start; ++t) {   // straddler interior rows
    const float a   = arow[t];
    const float4 h0 = loadh0(t);
    const float4 h1 = loadh1(t);
    acc0.x += a * h0.x; acc0.y += a * h0.y;
    acc0.z += a * h0.z; acc0.w += a * h0.w;
    acc1.x += a * h1.x; acc1.y += a * h1.y;
    acc1.z += a * h1.z; acc1.w += a * h1.w;
  }

  // Replay chunk tc with depth-2 row prefetch; close/store owned segments.
  float4 c0 = loadh0(t_start);
  float4 c1 = loadh1(t_start);
  for (int j = 0; j < TCHUNK; ++j) {
    const int t  = t_start + j;
    const int tn = (j + 1 < TCHUNK) ? t + 1 : t;   // clamp in-chunk
    const float4 n0 = loadh0(tn);            // issue BEFORE consuming c0/c1
    const float4 n1 = loadh1(tn);
    const float a     = arow[t];             // uniform scalar load
    const float integ = I + a;               // reference op order
    const bool  fire  = integ > kThresh;     // wave-uniform
    if (fire) {
      const float cw = 1.0f - I;             // dist_completion
      acc0.x += cw * c0.x; acc0.y += cw * c0.y;
      acc0.z += cw * c0.z; acc0.w += cw * c0.w;
      acc1.x += cw * c1.x; acc1.y += cw * c1.y;
      acc1.z += cw * c1.z; acc1.w += cw * c1.w;
      if (s < Ln) {
        float* op = out + ((size_t)b * Ln + s) * Hn + col;
        *reinterpret_cast<float4*>(op)     = acc0;
        *reinterpret_cast<float4*>(op + 4) = acc1;
      }
      const float rem = a - cw;              // remainds -> opens next segment
      acc0.x = rem * c0.x; acc0.y = rem * c0.y;
      acc0.z = rem * c0.z; acc0.w = rem * c0.w;
      acc1.x = rem * c1.x; acc1.y = rem * c1.y;
      acc1.z = rem * c1.z; acc1.w = rem * c1.w;
      s += 1;
      I  = integ - 1.0f;
    } else {
      acc0.x += a * c0.x; acc0.y += a * c0.y;
      acc0.z += a * c0.z; acc0.w += a * c0.w;
      acc1.x += a * c1.x; acc1.y += a * c1.y;
      acc1.z += a * c1.z; acc1.w += a * c1.w;
      I = integ;
    }
    c0 = n0; c1 = n1;
  }
  // Open tail is owned by consumer (tc+1); nothing more to store...
  if (tc == NTCH - 1) {                      // ...except zero-fill at the end
    const float4 z = make_float4(0.f, 0.f, 0.f, 0.f);
    for (int s2 = s; s2 < Ln; ++s2) {
      float* op = out + ((size_t)b * Ln + s2) * Hn + col;
      *reinterpret_cast<float4*>(op)     = z;
      *reinterpret_cast<float4*>(op + 4) = z;
    }
  }
}

extern "C" void kernel_launch(void* const* d_in, const int* in_sizes, int n_in,
                              void* d_out, int out_size, void* d_ws, size_t ws_size,
                              hipStream_t stream) {
  const float* hidden = (const float*)d_in[0];
  const float* alphas = (const float*)d_in[1];
  float* out = (float*)d_out;

  // ws layout: meta[Bn*MSTRIDE] u64 (32 KB, memset each call -- poison 0xAA
  // would read as published since bit30 of 0xAAAAAAAA is set).
  uint64_t* meta = (uint64_t*)d_ws;
  hipMemsetAsync(meta, 0, (size_t)Bn * MSTRIDE * sizeof(uint64_t), stream);

  const int nblocks = Bn + NTCH * Bn;   // 32 producers + 3200 consumers
  cif_fused_kernel<<<nblocks, 64, 0, stream>>>(hidden, alphas, meta, out);
}